// Round 5
// baseline (115.812 us; speedup 1.0000x reference)
//
#include <hip/hip_runtime.h>

// Deterministic two-pass segment sum over SORTED ray_indices.
// Kernel A: stream idx once, scatter run boundaries -> ray_start[n_rays+1]
//           in d_ws (handles empty rays; every entry written exactly once).
// Kernel B: one wave per ray. Lanes read the ray's samples coalesced
//           (consecutive dwords), shuffle-reduce, lane 0 plain-stores the
//           float3. No atomics, no memset, every out element written once.

#define A_SPT 8   // samples per thread in boundary kernel

__global__ __launch_bounds__(256) void ray_start_kernel(
    const int* __restrict__ idx,        // [n] sorted
    int*       __restrict__ ray_start,  // [n_rays+1] in d_ws
    int n, int n_rays)
{
    long long base = ((long long)blockIdx.x * blockDim.x + threadIdx.x) * A_SPT;
    if (base >= n) return;

    int v[A_SPT + 1];
    if (base + A_SPT < n) {
        int4 a = *(const int4*)(idx + base);
        int4 b = *(const int4*)(idx + base + 4);
        v[0]=a.x; v[1]=a.y; v[2]=a.z; v[3]=a.w;
        v[4]=b.x; v[5]=b.y; v[6]=b.z; v[7]=b.w;
        v[8] = idx[base + 8];
    } else {
        #pragma unroll
        for (int k = 0; k <= A_SPT; ++k) {
            long long s = base + k;
            v[k] = (s < n) ? idx[s] : n_rays;   // sentinel fills (last id, n_rays]
        }
    }

    if (base == 0) {
        // rays before the first sample (empty) + ray idx[0] start at 0
        for (int q = 0; q <= v[0]; ++q) ray_start[q] = 0;
    }
    #pragma unroll
    for (int k = 0; k < A_SPT; ++k) {
        int a = v[k], b = v[k + 1];
        // boundary between sample i=base+k (id a) and i+1 (id b):
        // rays a+1..b start at i+1 (rays a+1..b-1 are empty).
        for (int q = a + 1; q <= b; ++q) ray_start[q] = (int)(base + k + 1);
    }
}

__global__ __launch_bounds__(256) void integrate_rays_kernel(
    const float* __restrict__ rgb,       // [n, 3]
    const float* __restrict__ w,         // [n, 1]
    const int*   __restrict__ ray_start, // [n_rays+1]
    float*       __restrict__ out,       // [n_rays, 3]
    int n_rays)
{
    const int lane = threadIdx.x & 63;
    const int ray  = blockIdx.x * (blockDim.x >> 6) + (threadIdx.x >> 6);
    if (ray >= n_rays) return;           // wave-uniform

    const int s0 = ray_start[ray];
    const int s1 = ray_start[ray + 1];

    float ax = 0.f, ay = 0.f, az = 0.f;
    for (int s = s0 + lane; s < s1; s += 64) {   // coalesced: lane i -> sample s0+i
        float wv = w[s];
        ax = fmaf(wv, rgb[3 * s + 0], ax);
        ay = fmaf(wv, rgb[3 * s + 1], ay);
        az = fmaf(wv, rgb[3 * s + 2], az);
    }

    #pragma unroll
    for (int d = 1; d < 64; d <<= 1) {
        ax += __shfl_down(ax, d);
        ay += __shfl_down(ay, d);
        az += __shfl_down(az, d);
    }

    if (lane == 0) {
        out[3 * ray + 0] = ax;
        out[3 * ray + 1] = ay;
        out[3 * ray + 2] = az;
    }
}

extern "C" void kernel_launch(void* const* d_in, const int* in_sizes, int n_in,
                              void* d_out, int out_size, void* d_ws, size_t ws_size,
                              hipStream_t stream) {
    const float* rgb = (const float*)d_in[0];   // [n,3] f32
    const float* w   = (const float*)d_in[1];   // [n,1] f32
    const int*   idx = (const int*)  d_in[2];   // [n]   i32 sorted
    float*       out = (float*)d_out;           // [n_rays,3] f32
    int*   ray_start = (int*)d_ws;              // [n_rays+1] scratch

    int n      = in_sizes[2];
    int n_rays = out_size / 3;

    // Pass A: boundaries (d_ws is re-poisoned each call; A rewrites all entries)
    long long a_threads = ((long long)n + A_SPT - 1) / A_SPT;
    int a_blocks = (int)((a_threads + 255) / 256);
    ray_start_kernel<<<a_blocks, 256, 0, stream>>>(idx, ray_start, n, n_rays);

    // Pass B: one wave per ray, plain stores (no memset needed — every
    // out element is written exactly once).
    int rays_per_block = 256 / 64;
    int b_blocks = (n_rays + rays_per_block - 1) / rays_per_block;
    integrate_rays_kernel<<<b_blocks, 256, 0, stream>>>(rgb, w, ray_start, out, n_rays);
}

// Round 6
// 114.917 us; speedup vs baseline: 1.0078x; 1.0078x over previous
//
#include <hip/hip_runtime.h>

// Segmented (per-ray) weighted RGB sum over SORTED ray_indices.
// R6: R4's streaming structure (wave = 2 x 512-sample tiles, all loads up
// front, 16 waves/CU) + atomic elimination: runs COMPLETE inside a wave's
// 1024-sample span are plain-stored exactly once (sorted => contiguous =>
// race-free); only the wave's head/tail boundary pieces use atomicAdd
// (<=2 triples/wave ~ 4K total vs ~420K before). memset covers empty rays
// and atomic bases. Predicted: WRITE_SIZE 26MB -> ~1.5MB.

#define SPL 8                    // contiguous samples per lane
#define WAVE_SAMPLES (64 * SPL)  // 512 samples per tile
#define TPW 2                    // tiles per wave

struct Tile {
    int   ids[SPL];
    float ws[SPL], sx[SPL], sy[SPL], sz[SPL];
};

struct TileOut {                 // wave-uniform after process_tile
    int   fid, lid;              // first/last ray id in tile
    float Px, Py, Pz;            // prefix-run piece (ray fid)
    float Tx, Ty, Tz;            // tail-run piece (ray lid)
};

__device__ __forceinline__ void load_tile(const float* __restrict__ rgb,
                                          const float* __restrict__ w,
                                          const int*   __restrict__ idx,
                                          long long tbase, int lane, int n,
                                          Tile& T)
{
    const long long base = tbase + (long long)lane * SPL;
    if (base + SPL <= n) {
        int4   i0 = *(const int4*)(idx + base);
        int4   i1 = *(const int4*)(idx + base + 4);
        float4 w0 = *(const float4*)(w + base);
        float4 w1 = *(const float4*)(w + base + 4);
        const float4* r4 = (const float4*)(rgb + 3 * base);
        float4 r0 = r4[0], r1 = r4[1], r2 = r4[2];
        float4 r3 = r4[3], r4v = r4[4], r5 = r4[5];

        T.ids[0]=i0.x; T.ids[1]=i0.y; T.ids[2]=i0.z; T.ids[3]=i0.w;
        T.ids[4]=i1.x; T.ids[5]=i1.y; T.ids[6]=i1.z; T.ids[7]=i1.w;
        T.ws[0]=w0.x; T.ws[1]=w0.y; T.ws[2]=w0.z; T.ws[3]=w0.w;
        T.ws[4]=w1.x; T.ws[5]=w1.y; T.ws[6]=w1.z; T.ws[7]=w1.w;
        T.sx[0]=r0.x;  T.sy[0]=r0.y;  T.sz[0]=r0.z;
        T.sx[1]=r0.w;  T.sy[1]=r1.x;  T.sz[1]=r1.y;
        T.sx[2]=r1.z;  T.sy[2]=r1.w;  T.sz[2]=r2.x;
        T.sx[3]=r2.y;  T.sy[3]=r2.z;  T.sz[3]=r2.w;
        T.sx[4]=r3.x;  T.sy[4]=r3.y;  T.sz[4]=r3.z;
        T.sx[5]=r3.w;  T.sy[5]=r4v.x; T.sz[5]=r4v.y;
        T.sx[6]=r4v.z; T.sy[6]=r4v.w; T.sz[6]=r5.x;
        T.sx[7]=r5.y;  T.sy[7]=r5.z;  T.sz[7]=r5.w;
    } else {
        #pragma unroll
        for (int k = 0; k < SPL; ++k) {
            long long s  = base + k;
            bool      ok = (s < n);
            long long sc = ok ? s : (long long)(n - 1);
            T.ids[k] = idx[sc];
            T.ws[k]  = ok ? w[sc] : 0.0f;
            T.sx[k] = rgb[3*sc+0]; T.sy[k] = rgb[3*sc+1]; T.sz[k] = rgb[3*sc+2];
        }
    }
}

__device__ __forceinline__ void process_tile(const Tile& T, int lane,
                                             float* __restrict__ out,
                                             TileOut& R)
{
    // ---- Serial in-lane pass. Head piece (h*), interior complete segs
    // (plain store: run bounded by id-changes inside this lane), tail (a*).
    const int first = T.ids[0];
    int   cur = first;
    float ax = T.ws[0]*T.sx[0], ay = T.ws[0]*T.sy[0], az = T.ws[0]*T.sz[0];
    float hx = 0.f, hy = 0.f, hz = 0.f;
    bool  f = false;
    #pragma unroll
    for (int k = 1; k < SPL; ++k) {
        if (T.ids[k] != cur) {
            if (!f) { hx = ax; hy = ay; hz = az; f = true; }
            else {                       // complete interior run -> store
                out[cur*3+0] = ax; out[cur*3+1] = ay; out[cur*3+2] = az;
            }
            ax = ay = az = 0.f;
            cur = T.ids[k];
        }
        ax = fmaf(T.ws[k], T.sx[k], ax);
        ay = fmaf(T.ws[k], T.sy[k], ay);
        az = fmaf(T.ws[k], T.sz[k], az);
    }
    const int t_id = cur;

    // ---- Cross-lane segmented suffix scan over per-lane tail pieces.
    int  t_prev = __shfl_up(t_id, 1);
    bool edge   = (lane > 0) && (t_prev != first);   // ray changed at lane edge
    bool brk    = f || edge;
    unsigned long long bm = __ballot(brk);

    float Sx = ax, Sy = ay, Sz = az;
    #pragma unroll
    for (int d = 1; d < 64; d <<= 1) {
        float ox = __shfl_down(Sx, d);
        float oy = __shfl_down(Sy, d);
        float oz = __shfl_down(Sz, d);
        unsigned long long between = ((bm >> 1) >> lane) & ((1ull << d) - 1ull);
        bool cont = (lane + d < 64) && (between == 0);
        if (cont) { Sx += ox; Sy += oy; Sz += oz; }
    }

    const unsigned long long HM = bm | 1ull;         // lane 0 is always a head
    const int h_last = 63 - __builtin_clzll(HM);

    // Absorb: if the next head L broke due to an in-lane boundary with no
    // edge-change (run continues into L's head piece), add h*@L to the run.
    unsigned long long above = (lane < 63) ? (HM >> (lane + 1)) : 0ull;
    int  L  = above ? (lane + 1 + __builtin_ctzll(above)) : 64;
    int  Ls = (L < 64) ? L : 0;
    bool my_absorbed = f && (lane > 0) && !edge;     // head piece continues prev run
    int   absL = __shfl((int)my_absorbed, Ls);
    float ahx  = __shfl(hx, Ls), ahy = __shfl(hy, Ls), ahz = __shfl(hz, Ls);
    bool  doAbs = (L < 64) && absL;
    float Vx = Sx + (doAbs ? ahx : 0.f);
    float Vy = Sy + (doAbs ? ahy : 0.f);
    float Vz = Sz + (doAbs ? ahz : 0.f);

    // Complete-run stores within the tile:
    bool head = (lane == 0) || brk;
    bool isT  = (lane == h_last);
    if (head && !isT && !(lane == 0 && !f)) {        // complete scan-run
        out[t_id*3+0] = Vx; out[t_id*3+1] = Vy; out[t_id*3+2] = Vz;
    }
    if (f && (lane > 0) && edge) {                   // unabsorbed head piece:
        out[first*3+0] = hx; out[first*3+1] = hy; out[first*3+2] = hz;
    }

    // Handoff pieces (wave-uniform via broadcast):
    float pvx = f ? hx : Vx, pvy = f ? hy : Vy, pvz = f ? hz : Vz;
    R.fid = __shfl(first, 0);
    R.lid = __shfl(t_id, 63);
    R.Px  = __shfl(pvx, 0); R.Py = __shfl(pvy, 0); R.Pz = __shfl(pvz, 0);
    R.Tx  = __shfl(Vx, h_last); R.Ty = __shfl(Vy, h_last); R.Tz = __shfl(Vz, h_last);
}

__global__ __launch_bounds__(256, 4) void integrate_kernel(
    const float* __restrict__ rgb,      // [n, 3]
    const float* __restrict__ w,        // [n, 1]
    const int*   __restrict__ idx,      // [n] sorted
    float*       __restrict__ out,      // [n_rays, 3], pre-zeroed
    int n)
{
    const int lane = threadIdx.x & 63;
    const long long wave = ((long long)blockIdx.x * blockDim.x + threadIdx.x) >> 6;
    const long long b0 = wave * (TPW * (long long)WAVE_SAMPLES);
    if (b0 >= n) return;                 // wave-uniform exit
    const long long b1 = b0 + WAVE_SAMPLES;
    const bool has1 = (b1 < n);

    Tile T0, T1;
    load_tile(rgb, w, idx, b0, lane, n, T0);
    if (has1) load_tile(rgb, w, idx, b1, lane, n, T1);

    TileOut R0, R1;
    process_tile(T0, lane, out, R0);
    if (has1) process_tile(T1, lane, out, R1);

    // ---- Wave-level merge of boundary pieces (lane 0). Wave-edge pieces
    // may be shared with neighbor waves -> atomicAdd (memset'ed base).
    // Wave-interior complete pieces -> plain store.
    if (lane == 0) {
        bool s0 = (R0.fid == R0.lid);    // tile0 is a single run
        if (!has1) {
            atomicAdd(&out[R0.fid*3+0], R0.Px);
            atomicAdd(&out[R0.fid*3+1], R0.Py);
            atomicAdd(&out[R0.fid*3+2], R0.Pz);
            if (!s0) {
                atomicAdd(&out[R0.lid*3+0], R0.Tx);
                atomicAdd(&out[R0.lid*3+1], R0.Ty);
                atomicAdd(&out[R0.lid*3+2], R0.Tz);
            }
        } else {
            bool s1 = (R1.fid == R1.lid);
            if (s0 && s1) {
                if (R0.fid == R1.fid) {  // whole wave one ray
                    atomicAdd(&out[R0.fid*3+0], R0.Px + R1.Px);
                    atomicAdd(&out[R0.fid*3+1], R0.Py + R1.Py);
                    atomicAdd(&out[R0.fid*3+2], R0.Pz + R1.Pz);
                } else {
                    atomicAdd(&out[R0.fid*3+0], R0.Px);
                    atomicAdd(&out[R0.fid*3+1], R0.Py);
                    atomicAdd(&out[R0.fid*3+2], R0.Pz);
                    atomicAdd(&out[R1.fid*3+0], R1.Px);
                    atomicAdd(&out[R1.fid*3+1], R1.Py);
                    atomicAdd(&out[R1.fid*3+2], R1.Pz);
                }
            } else if (s0) {             // tile0 single, tile1 multi
                if (R0.fid == R1.fid) {
                    atomicAdd(&out[R0.fid*3+0], R0.Px + R1.Px);
                    atomicAdd(&out[R0.fid*3+1], R0.Py + R1.Py);
                    atomicAdd(&out[R0.fid*3+2], R0.Pz + R1.Pz);
                } else {
                    atomicAdd(&out[R0.fid*3+0], R0.Px);
                    atomicAdd(&out[R0.fid*3+1], R0.Py);
                    atomicAdd(&out[R0.fid*3+2], R0.Pz);
                    out[R1.fid*3+0] = R1.Px;   // complete interior run
                    out[R1.fid*3+1] = R1.Py;
                    out[R1.fid*3+2] = R1.Pz;
                }
                atomicAdd(&out[R1.lid*3+0], R1.Tx);
                atomicAdd(&out[R1.lid*3+1], R1.Ty);
                atomicAdd(&out[R1.lid*3+2], R1.Tz);
            } else if (s1) {             // tile0 multi, tile1 single
                atomicAdd(&out[R0.fid*3+0], R0.Px);
                atomicAdd(&out[R0.fid*3+1], R0.Py);
                atomicAdd(&out[R0.fid*3+2], R0.Pz);
                if (R0.lid == R1.fid) {
                    atomicAdd(&out[R0.lid*3+0], R0.Tx + R1.Px);
                    atomicAdd(&out[R0.lid*3+1], R0.Ty + R1.Py);
                    atomicAdd(&out[R0.lid*3+2], R0.Tz + R1.Pz);
                } else {
                    out[R0.lid*3+0] = R0.Tx;   // complete interior run
                    out[R0.lid*3+1] = R0.Ty;
                    out[R0.lid*3+2] = R0.Tz;
                    atomicAdd(&out[R1.fid*3+0], R1.Px);
                    atomicAdd(&out[R1.fid*3+1], R1.Py);
                    atomicAdd(&out[R1.fid*3+2], R1.Pz);
                }
            } else {                     // both multi
                atomicAdd(&out[R0.fid*3+0], R0.Px);
                atomicAdd(&out[R0.fid*3+1], R0.Py);
                atomicAdd(&out[R0.fid*3+2], R0.Pz);
                if (R0.lid == R1.fid) {  // merged interior run
                    out[R0.lid*3+0] = R0.Tx + R1.Px;
                    out[R0.lid*3+1] = R0.Ty + R1.Py;
                    out[R0.lid*3+2] = R0.Tz + R1.Pz;
                } else {
                    out[R0.lid*3+0] = R0.Tx;
                    out[R0.lid*3+1] = R0.Ty;
                    out[R0.lid*3+2] = R0.Tz;
                    out[R1.fid*3+0] = R1.Px;
                    out[R1.fid*3+1] = R1.Py;
                    out[R1.fid*3+2] = R1.Pz;
                }
                atomicAdd(&out[R1.lid*3+0], R1.Tx);
                atomicAdd(&out[R1.lid*3+1], R1.Ty);
                atomicAdd(&out[R1.lid*3+2], R1.Tz);
            }
        }
    }
}

extern "C" void kernel_launch(void* const* d_in, const int* in_sizes, int n_in,
                              void* d_out, int out_size, void* d_ws, size_t ws_size,
                              hipStream_t stream) {
    const float* rgb = (const float*)d_in[0];   // [n,3] f32
    const float* w   = (const float*)d_in[1];   // [n,1] f32
    const int*   idx = (const int*)  d_in[2];   // [n]   i32 sorted
    float*       out = (float*)d_out;           // [n_rays,3] f32

    int n = in_sizes[2];

    // Zero-init: empty rays keep 0; wave-boundary rays need a 0 atomic base.
    hipMemsetAsync(d_out, 0, (size_t)out_size * sizeof(float), stream);

    long long tiles  = ((long long)n + WAVE_SAMPLES - 1) / WAVE_SAMPLES;
    long long waves  = (tiles + TPW - 1) / TPW;
    long long blocks = (waves + 3) / 4;          // 4 waves (256 thr) per block
    integrate_kernel<<<(int)blocks, 256, 0, stream>>>(rgb, w, idx, out, n);
}

// Round 7
// 109.294 us; speedup vs baseline: 1.0596x; 1.0515x over previous
//
#include <hip/hip_runtime.h>

// Segmented (per-ray) weighted RGB sum over SORTED ray_indices.
// R7 = R4 (wave = 2 x 512-sample tiles, all loads up front, 16 waves/CU)
// + head-piece absorption: lane L's head piece (boundary strictly inside
// lane L, f && !edge) is pre-added into lane L-1's tail value via 4
// shuffles, so the segmented suffix scan's head flush already contains it
// and the separate per-lane f-flush atomic disappears. Atomic triples/tile
// ~17 -> ~10. Zero extra register cost vs R4 (drops the f-flush branch).

#define SPL 8                    // contiguous samples per lane
#define WAVE_SAMPLES (64 * SPL)  // 512 samples per tile
#define TPW 2                    // tiles per wave

struct Tile {
    int   ids[SPL];
    float ws[SPL], sx[SPL], sy[SPL], sz[SPL];
};

__device__ __forceinline__ void load_tile(const float* __restrict__ rgb,
                                          const float* __restrict__ w,
                                          const int*   __restrict__ idx,
                                          long long tbase, int lane, int n,
                                          Tile& T)
{
    const long long base = tbase + (long long)lane * SPL;
    if (base + SPL <= n) {
        int4   i0 = *(const int4*)(idx + base);
        int4   i1 = *(const int4*)(idx + base + 4);
        float4 w0 = *(const float4*)(w + base);
        float4 w1 = *(const float4*)(w + base + 4);
        const float4* r4 = (const float4*)(rgb + 3 * base);
        float4 r0 = r4[0], r1 = r4[1], r2 = r4[2];
        float4 r3 = r4[3], r4v = r4[4], r5 = r4[5];

        T.ids[0]=i0.x; T.ids[1]=i0.y; T.ids[2]=i0.z; T.ids[3]=i0.w;
        T.ids[4]=i1.x; T.ids[5]=i1.y; T.ids[6]=i1.z; T.ids[7]=i1.w;
        T.ws[0]=w0.x; T.ws[1]=w0.y; T.ws[2]=w0.z; T.ws[3]=w0.w;
        T.ws[4]=w1.x; T.ws[5]=w1.y; T.ws[6]=w1.z; T.ws[7]=w1.w;
        T.sx[0]=r0.x;  T.sy[0]=r0.y;  T.sz[0]=r0.z;
        T.sx[1]=r0.w;  T.sy[1]=r1.x;  T.sz[1]=r1.y;
        T.sx[2]=r1.z;  T.sy[2]=r1.w;  T.sz[2]=r2.x;
        T.sx[3]=r2.y;  T.sy[3]=r2.z;  T.sz[3]=r2.w;
        T.sx[4]=r3.x;  T.sy[4]=r3.y;  T.sz[4]=r3.z;
        T.sx[5]=r3.w;  T.sy[5]=r4v.x; T.sz[5]=r4v.y;
        T.sx[6]=r4v.z; T.sy[6]=r4v.w; T.sz[6]=r5.x;
        T.sx[7]=r5.y;  T.sy[7]=r5.z;  T.sz[7]=r5.w;
    } else {
        #pragma unroll
        for (int k = 0; k < SPL; ++k) {
            long long s  = base + k;
            bool      ok = (s < n);
            long long sc = ok ? s : (long long)(n - 1);
            T.ids[k] = idx[sc];
            T.ws[k]  = ok ? w[sc] : 0.0f;
            T.sx[k] = rgb[3*sc+0]; T.sy[k] = rgb[3*sc+1]; T.sz[k] = rgb[3*sc+2];
        }
    }
}

__device__ __forceinline__ void process_tile(const Tile& T, int lane,
                                             float* __restrict__ out)
{
    // Serial in-lane pass: head piece h* (first boundary), interior
    // complete segs (atomic, rare), tail a*.
    const int first = T.ids[0];
    int   cur = first;
    float ax = T.ws[0]*T.sx[0], ay = T.ws[0]*T.sy[0], az = T.ws[0]*T.sz[0];
    float hx = 0.f, hy = 0.f, hz = 0.f;
    bool  f = false;
    #pragma unroll
    for (int k = 1; k < SPL; ++k) {
        if (T.ids[k] != cur) {
            if (!f) { hx = ax; hy = ay; hz = az; f = true; }
            else {
                atomicAdd(&out[cur*3+0], ax);
                atomicAdd(&out[cur*3+1], ay);
                atomicAdd(&out[cur*3+2], az);
            }
            ax = ay = az = 0.f;
            cur = T.ids[k];
        }
        ax = fmaf(T.ws[k], T.sx[k], ax);
        ay = fmaf(T.ws[k], T.sy[k], ay);
        az = fmaf(T.ws[k], T.sz[k], az);
    }
    const int t_id = cur;

    int  t_prev = __shfl_up(t_id, 1);
    bool edge   = (lane > 0) && (t_prev != first);  // run ended exactly at lane edge
    bool brk    = f || edge;
    unsigned long long bm = __ballot(brk);

    // Absorption: if lane L+1's head piece terminates MY run (f && !edge
    // there), pre-add it into my tail value. The scan head then flushes the
    // complete run in one atomic; no separate f-flush needed.
    bool term  = f && !edge;                        // my h continues prev lane's run
    int   nt   = __shfl_down((int)term, 1);
    float nhx  = __shfl_down(hx, 1);
    float nhy  = __shfl_down(hy, 1);
    float nhz  = __shfl_down(hz, 1);
    bool  absb = (lane < 63) && nt;
    float Sx = ax + (absb ? nhx : 0.f);
    float Sy = ay + (absb ? nhy : 0.f);
    float Sz = az + (absb ? nhz : 0.f);

    // Segmented suffix scan over (absorbed) tail pieces.
    #pragma unroll
    for (int d = 1; d < 64; d <<= 1) {
        float ox = __shfl_down(Sx, d);
        float oy = __shfl_down(Sy, d);
        float oz = __shfl_down(Sz, d);
        unsigned long long between = ((bm >> 1) >> lane) & ((1ull << d) - 1ull);
        bool cont = (lane + d < 64) && (between == 0);
        if (cont) { Sx += ox; Sy += oy; Sz += oz; }
    }

    if (lane == 0 || brk) {                         // run flush (includes absorbed h)
        atomicAdd(&out[t_id*3+0], Sx);
        atomicAdd(&out[t_id*3+1], Sy);
        atomicAdd(&out[t_id*3+2], Sz);
    }
    // Unabsorbed head pieces: tile prefix (lane 0) or standalone head-run
    // (boundary at lane edge AND inside the lane) — both rare.
    if (f && (edge || lane == 0)) {
        atomicAdd(&out[first*3+0], hx);
        atomicAdd(&out[first*3+1], hy);
        atomicAdd(&out[first*3+2], hz);
    }
}

__global__ __launch_bounds__(256, 4) void integrate_kernel(
    const float* __restrict__ rgb,      // [n, 3]
    const float* __restrict__ w,        // [n, 1]
    const int*   __restrict__ idx,      // [n] sorted
    float*       __restrict__ out,      // [n_rays, 3], pre-zeroed
    int n)
{
    const int lane = threadIdx.x & 63;
    const long long wave = ((long long)blockIdx.x * blockDim.x + threadIdx.x) >> 6;
    const long long b0 = wave * (TPW * (long long)WAVE_SAMPLES);
    if (b0 >= n) return;                 // wave-uniform exit
    const long long b1 = b0 + WAVE_SAMPLES;
    const bool has1 = (b1 < n);

    Tile T0, T1;
    load_tile(rgb, w, idx, b0, lane, n, T0);
    if (has1) load_tile(rgb, w, idx, b1, lane, n, T1);

    process_tile(T0, lane, out);
    if (has1) process_tile(T1, lane, out);
}

extern "C" void kernel_launch(void* const* d_in, const int* in_sizes, int n_in,
                              void* d_out, int out_size, void* d_ws, size_t ws_size,
                              hipStream_t stream) {
    const float* rgb = (const float*)d_in[0];   // [n,3] f32
    const float* w   = (const float*)d_in[1];   // [n,1] f32
    const int*   idx = (const int*)  d_in[2];   // [n]   i32 sorted
    float*       out = (float*)d_out;           // [n_rays,3] f32

    int n = in_sizes[2];

    // Output is re-poisoned to 0xAA before every timed launch — zero it
    // (empty rays stay 0; atomics need a zero base).
    hipMemsetAsync(d_out, 0, (size_t)out_size * sizeof(float), stream);

    long long tiles  = ((long long)n + WAVE_SAMPLES - 1) / WAVE_SAMPLES;
    long long waves  = (tiles + TPW - 1) / TPW;
    long long blocks = (waves + 3) / 4;          // 4 waves (256 thr) per block
    integrate_kernel<<<(int)blocks, 256, 0, stream>>>(rgb, w, idx, out, n);
}